// Round 6
// baseline (409.966 us; speedup 1.0000x reference)
//
#include <hip/hip_runtime.h>
#include <math.h>

#define NB 64
#define SS 512
#define HH 768
#define LL 20
#define MS 8
#define NSPC 9   // MAX_SPANS+1

// ---- output layout (floats), reference return order ----
#define OFF_START 0
#define OFF_END   (NB*SS)
#define OFF_SPANS (2*NB*SS)
#define OFF_NSP   (2*NB*SS + NB*LL)
#define OFF_POL   (2*NB*SS + NB*LL + NB*NSPC)
#define OFF_SOH   (2*NB*SS + 2*NB*LL + NB*NSPC)
#define OFF_EOH   (3*NB*SS + 2*NB*LL + NB*NSPC)
#define OFF_LOH   (4*NB*SS + 2*NB*LL + NB*NSPC)

struct WS {
  float fsl[NB][LL];          // full_seq_logits
  float mls[NB][MS][LL];      // per-span softmax rows
  int   nspans[NB];
  int   fslarg[NB];           // argmax(full_seq_logits)
  int   cnt[NB];
  int   out_s[NB][MS];
  int   out_e[NB][MS];
  int   slabel[NB][MS];
  float candSV[NB][16][MS];   // per-block top-8 candidates (starts)
  int   candSI[NB][16][MS];
  float candEV[NB][16][MS];   // (ends)
  int   candEI[NB][16][MS];
  unsigned ctrA[NB];          // zeroed by memsetAsync each call
  unsigned ctrC[NB];          // zeroed by kA's seq block each call
};

// merge 128 candidates -> top-8, run selection automaton, write one-hots.
// called by exactly one 256-thread block per item.
__device__ void merge_select(int b, float* __restrict__ out, WS* __restrict__ ws)
{
  __shared__ int topI[2][MS];
  __shared__ int m_cnt, m_single;
  __shared__ int m_os[MS], m_oe[MS];
  int t = threadIdx.x;
  int wave = t >> 6, lane = t & 63;

  // extraction: wave 0 -> starts, wave 1 -> ends; 128 candidates, 2/lane
  if (wave < 2) {
    const float* cv = wave ? &ws->candEV[b][0][0] : &ws->candSV[b][0][0];
    const int*   ci = wave ? &ws->candEI[b][0][0] : &ws->candSI[b][0][0];
    float c0v = cv[lane], c1v = cv[lane + 64];
    int   c0i = ci[lane], c1i = ci[lane + 64];
    #pragma unroll
    for (int k = 0; k < MS; ++k) {
      float lv = c0v; int li = c0i;
      if (c1v > lv || (c1v == lv && c1i < li)) { lv = c1v; li = c1i; }
      #pragma unroll
      for (int m = 32; m >= 1; m >>= 1) {
        float ov = __shfl_xor(lv, m); int oi = __shfl_xor(li, m);
        if (ov > lv || (ov == lv && oi < li)) { lv = ov; li = oi; }
      }
      if (lane == 0) topI[wave][k] = li;
      if (c0i == li) c0v = -INFINITY;
      if (c1i == li) c1v = -INFINITY;
    }
  }
  __syncthreads();

  int n = ws->nspans[b];

  // selection automaton: wave 0, wave-uniform state
  if (wave == 0) {
    int xs = SS, xe = SS;
    if (lane < MS && lane < n) { xs = topI[0][lane]; xe = topI[1][lane]; }
    int rs = 0, re = 0;
    #pragma unroll
    for (int j = 0; j < MS; ++j) {
      int xj = __shfl(xs, j);
      if (xj < xs || (xj == xs && j < lane)) ++rs;
      int yj = __shfl(xe, j);
      if (yj < xe || (yj == xe && j < lane)) ++re;
    }
    int ss_srt = 0, es_srt = 0;
    #pragma unroll
    for (int j = 0; j < MS; ++j) {
      int xj = __shfl(xs, j); int rj = __shfl(rs, j);
      if (rj == lane) ss_srt = xj;
      int yj = __shfl(xe, j); int qj = __shfl(re, j);
      if (qj == lane) es_srt = yj;
    }
    int si = 0, ei = 0, last = 0, rem = n, cnt = 0;
    int my_os = 0, my_oe = 0;
    for (int it = 0; it < 2*MS; ++it) {
      bool active = (rem > 0) && (si < n) && (ei < n);
      int s = __shfl(ss_srt, si < MS ? si : MS - 1);
      int e = __shfl(es_srt, ei < MS ? ei : MS - 1);
      bool accept = active && (e > s) && (s >= last);
      bool ince = active && !accept && (e <= s);
      bool incs = active && !accept && (e > s);
      if (accept) {
        if (lane == cnt) { my_os = s; my_oe = e; }
        last = e; ++cnt; --rem; ++si; ++ei;
      } else {
        si += incs ? 1 : 0; ei += ince ? 1 : 0;
      }
    }
    if (lane < MS) {
      m_os[lane] = my_os; m_oe[lane] = my_oe;
      ws->out_s[b][lane] = my_os; ws->out_e[b][lane] = my_oe;
    }
    if (lane == 0) {
      m_cnt = cnt; m_single = (n <= 1) ? 1 : 0;
      ws->cnt[b] = cnt;
    }
  }
  __syncthreads();

  int cnt = m_cnt, single = m_single;
  #pragma unroll
  for (int pp = 0; pp < 2; ++pp) {
    int pos = t + pp * 256;
    float sval = 0.f, eval = 0.f;
    if (single) {
      if (pos == topI[0][0]) sval = 1.f;   // first-occurrence argmax
      if (pos == topI[1][0]) eval = 1.f;
    } else {
      for (int i = 0; i < cnt; ++i) {
        if (pos == m_os[i]) sval = 1.f;
        if (pos == m_oe[i]) eval = 1.f;
      }
    }
    out[OFF_SOH + b*SS + pos] = sval;
    out[OFF_EOH + b*SS + pos] = eval;
  }
}

// ---------------- kA: token logits + seq projections + fused select ----------------
// blocks [0,1024): 32 rows each (4 waves x 8 rows); 16 blocks per item.
// blocks [1024,1088): per-item seq_rep projections.
// last arriver of the 17 blocks per item runs merge_select.
__global__ __launch_bounds__(256) void kA(
    const float4* __restrict__ tok,
    const float* __restrict__ wstart, const float* __restrict__ bstart,
    const float* __restrict__ wend,  const float* __restrict__ bend,
    const float* __restrict__ seq,
    const float* __restrict__ Wspan, const float* __restrict__ bspan,
    const float* __restrict__ Wnsp,  const float* __restrict__ bnsp,
    float* __restrict__ out, WS* __restrict__ ws)
{
  int t = threadIdx.x;
  int wave = t >> 6, lane = t & 63;
  int b;

  if (blockIdx.x < 1024) {
    b = blockIdx.x >> 4;
    int blk = blockIdx.x & 15;
    __shared__ float4 shs[HH/4], she[HH/4];
    __shared__ float lvS[32], lvE[32];
    __shared__ int   liS[32], liE[32];
    const float4* wsg = (const float4*)wstart;
    const float4* weg = (const float4*)wend;
    for (int i = t; i < HH/4; i += 256) { shs[i] = wsg[i]; she[i] = weg[i]; }
    __syncthreads();
    int r0 = blockIdx.x * 32 + wave * 8;
    const float4* base = tok + (size_t)r0 * (HH/4);
    float as[8] = {0.f,0.f,0.f,0.f,0.f,0.f,0.f,0.f};
    float ae[8] = {0.f,0.f,0.f,0.f,0.f,0.f,0.f,0.f};
    #pragma unroll
    for (int k = 0; k < 3; ++k) {
      int idx = k*64 + lane;
      float4 a = shs[idx], c = she[idx];
      #pragma unroll
      for (int j = 0; j < 8; ++j) {
        float4 x = base[(size_t)j * (HH/4) + idx];
        as[j] += x.x*a.x + x.y*a.y + x.z*a.z + x.w*a.w;
        ae[j] += x.x*c.x + x.y*c.y + x.z*c.z + x.w*c.w;
      }
    }
    float b0 = bstart[0], b1 = bend[0];
    #pragma unroll
    for (int j = 0; j < 8; ++j) {
      float a = as[j], e = ae[j];
      for (int off = 32; off >= 1; off >>= 1) { a += __shfl_down(a, off); e += __shfl_down(e, off); }
      if (lane == 0) {
        out[OFF_START + r0 + j] = a + b0;
        out[OFF_END   + r0 + j] = e + b1;
        int slot = wave*8 + j;
        lvS[slot] = a + b0; lvE[slot] = e + b1;
        int rl = blk*32 + wave*8 + j;      // row index within item
        liS[slot] = rl; liE[slot] = rl;
      }
    }
    __syncthreads();
    // per-block top-8 via rank selection (wave 0 -> S, wave 1 -> E)
    if (wave < 2) {
      float v = -INFINITY; int idx = 0x7fffffff;
      if (lane < 32) {
        v = wave ? lvE[lane] : lvS[lane];
        idx = wave ? liE[lane] : liS[lane];
      }
      int rank = 0;
      #pragma unroll
      for (int j = 0; j < 32; ++j) {
        float vj = __shfl(v, j); int ij = __shfl(idx, j);
        if (vj > v || (vj == v && ij < idx)) ++rank;
      }
      if (lane < 32 && rank < MS) {
        if (wave == 0) { ws->candSV[b][blk][rank] = v; ws->candSI[b][blk][rank] = idx; }
        else           { ws->candEV[b][blk][rank] = v; ws->candEI[b][blk][rank] = idx; }
      }
    }
  } else {
    b = blockIdx.x - 1024;
    __shared__ float sh[HH];
    __shared__ float logits[LL + NSPC];
    for (int i = t; i < HH; i += 256) sh[i] = seq[b*HH + i];
    __syncthreads();
    for (int o = wave; o < LL + NSPC; o += 4) {
      float acc = 0.f;
      if (o < LL) {
        for (int k = 0; k < HH/64; ++k) { int h = lane + 64*k; acc += sh[h] * Wspan[h*LL + o]; }
      } else {
        int j = o - LL;
        for (int k = 0; k < HH/64; ++k) { int h = lane + 64*k; acc += sh[h] * Wnsp[h*NSPC + j]; }
      }
      for (int off = 32; off >= 1; off >>= 1) acc += __shfl_down(acc, off);
      if (lane == 0) logits[o] = acc + (o < LL ? bspan[o] : bnsp[o - LL]);
    }
    __syncthreads();
    if (t == 0) {
      int bi = 0; float bv = logits[LL];
      #pragma unroll
      for (int j = 1; j < NSPC; ++j) { float v = logits[LL + j]; if (v > bv) { bv = v; bi = j; } }
      ws->nspans[b] = bi;
      int fi = 0; float fv = logits[0];
      #pragma unroll
      for (int j = 1; j < LL; ++j) { float v = logits[j]; if (v > fv) { fv = v; fi = j; } }
      ws->fslarg[b] = fi;
      ws->ctrC[b] = 0;                    // reset kCD's counter for this call
    }
    if (t < LL)  ws->fsl[b][t] = logits[t];
    if (t < NSPC) out[OFF_NSP + b*NSPC + t] = logits[LL + t];
  }

  // arrival protocol: 17 participants per item (16 token + 1 seq block)
  __threadfence();
  __syncthreads();
  __shared__ unsigned sh_old;
  if (t == 0) sh_old = atomicAdd(&ws->ctrA[b], 1u);
  __syncthreads();
  if (sh_old == 16u) {
    __threadfence();
    merge_select(b, out, ws);
  }
}

// ---------------- kCD: span pooling + softmax, last block does combine+pol ----------------
__global__ __launch_bounds__(1024) void kCD(
    const float4* __restrict__ tok,
    const float* __restrict__ Wspan, const float* __restrict__ bspan,
    const float* __restrict__ seq,
    const float* __restrict__ Wpol, const float* __restrict__ bpol,
    float* __restrict__ out, WS* __restrict__ ws)
{
  int b = blockIdx.x >> 3;
  int i = blockIdx.x & (MS - 1);
  int t = threadIdx.x;
  int wave = t >> 6, lane = t & 63;
  int cnt = ws->cnt[b];

  if (i < cnt) {
    int s0 = ws->out_s[b][i], e0 = ws->out_e[b][i];
    int g = t >> 8;        // row group 0..3
    int tid = t & 255;
    __shared__ float4 part[4][HH/4];   // 12 KB
    __shared__ float pooled[HH];
    __shared__ float lg[LL];

    if (tid < HH/4) {
      float4 acc = make_float4(0.f, 0.f, 0.f, 0.f);
      const float4* base = tok + (size_t)b * SS * (HH/4) + tid;
      #pragma unroll 4
      for (int r = s0 + g; r <= e0; r += 4) {
        float4 x = base[(size_t)r * (HH/4)];
        acc.x += x.x; acc.y += x.y; acc.z += x.z; acc.w += x.w;
      }
      part[g][tid] = acc;
    }
    __syncthreads();
    if (t < HH/4) {
      float4 p0 = part[0][t], p1 = part[1][t], p2 = part[2][t], p3 = part[3][t];
      float inv = 1.f / (float)(e0 - s0 + 1);
      float4 s;
      s.x = (p0.x + p1.x + p2.x + p3.x) * inv;
      s.y = (p0.y + p1.y + p2.y + p3.y) * inv;
      s.z = (p0.z + p1.z + p2.z + p3.z) * inv;
      s.w = (p0.w + p1.w + p2.w + p3.w) * inv;
      ((float4*)pooled)[t] = s;
    }
    __syncthreads();
    for (int l = wave; l < LL; l += 16) {
      float acc = 0.f;
      for (int k = 0; k < HH/64; ++k) { int h = lane + 64*k; acc += pooled[h] * Wspan[h*LL + l]; }
      for (int off = 32; off >= 1; off >>= 1) acc += __shfl_down(acc, off);
      if (lane == 0) lg[l] = acc + bspan[l];
    }
    __syncthreads();
    if (t == 0) {
      float v[LL]; float mx = -INFINITY;
      #pragma unroll
      for (int l = 0; l < LL; ++l) { v[l] = lg[l]; mx = fmaxf(mx, v[l]); }
      int am = 0; float av = v[0];
      #pragma unroll
      for (int l = 1; l < LL; ++l) if (v[l] > av) { av = v[l]; am = l; }
      float sum = 0.f;
      #pragma unroll
      for (int l = 0; l < LL; ++l) { v[l] = expf(v[l] - mx); sum += v[l]; }
      float isum = 1.f / sum;
      #pragma unroll
      for (int l = 0; l < LL; ++l) ws->mls[b][i][l] = v[l] * isum;
      ws->slabel[b][i] = am;
    }
  }

  // arrival protocol: 8 blocks per item; last one does the combine + pol
  __threadfence();
  __syncthreads();
  __shared__ unsigned sh_old;
  if (t == 0) sh_old = atomicAdd(&ws->ctrC[b], 1u);
  __syncthreads();
  if (sh_old != (unsigned)(MS - 1)) return;
  __threadfence();

  __shared__ float sp[LL];
  __shared__ float fsl_soft[LL];
  int n = ws->nspans[b];
  int single = (n <= 1) ? 1 : 0;
  int fa = ws->fslarg[b];
  if (t == 0) {
    float lg2[LL]; float mx = -INFINITY;
    #pragma unroll
    for (int l = 0; l < LL; ++l) { lg2[l] = ws->fsl[b][l]; mx = fmaxf(mx, lg2[l]); }
    float sum = 0.f;
    #pragma unroll
    for (int l = 0; l < LL; ++l) { lg2[l] = expf(lg2[l] - mx); sum += lg2[l]; }
    float isum = 1.f / sum;
    #pragma unroll
    for (int l = 0; l < LL; ++l) fsl_soft[l] = lg2[l] * isum;
  }
  __syncthreads();
  if (t < LL) {
    float v;
    if (single) v = fsl_soft[t];
    else if (cnt > 0) { v = -INFINITY; for (int k = 0; k < cnt; ++k) v = fmaxf(v, ws->mls[b][k][t]); }
    else v = 0.f;
    sp[t] = v;
    out[OFF_SPANS + b*LL + t] = v;
    float lo = 0.f;
    if (single || cnt == 0) lo = (t == fa) ? 1.f : 0.f;
    else { for (int k = 0; k < cnt; ++k) if (ws->slabel[b][k] == t) lo = 1.f; }
    out[OFF_LOH + b*LL + t] = lo;
  }
  __syncthreads();
  const float* seqb = seq + b*HH;
  for (int l = wave; l < LL; l += 16) {
    float acc = 0.f;
    for (int k = 0; k < 13; ++k) {
      int h = lane + 64*k;
      if (h < HH + LL) {
        float v = (h < HH) ? seqb[h] : sp[h - HH];
        acc += v * Wpol[h*LL + l];
      }
    }
    for (int off = 32; off >= 1; off >>= 1) acc += __shfl_down(acc, off);
    if (lane == 0) out[OFF_POL + b*LL + l] = acc + bpol[l];
  }
}

extern "C" void kernel_launch(void* const* d_in, const int* in_sizes, int n_in,
                              void* d_out, int out_size, void* d_ws, size_t ws_size,
                              hipStream_t stream)
{
  const float* tok    = (const float*)d_in[0];
  const float* seq    = (const float*)d_in[1];
  const float* wstart = (const float*)d_in[2];
  const float* bstart = (const float*)d_in[3];
  const float* wend   = (const float*)d_in[4];
  const float* bend   = (const float*)d_in[5];
  const float* Wnsp   = (const float*)d_in[6];
  const float* bnsp   = (const float*)d_in[7];
  const float* Wspan  = (const float*)d_in[8];
  const float* bspan  = (const float*)d_in[9];
  const float* Wpol   = (const float*)d_in[10];
  const float* bpol   = (const float*)d_in[11];
  float* out = (float*)d_out;
  WS* ws = (WS*)d_ws;

  // zero the kA arrival counters (256 B; poison-proof)
  hipMemsetAsync(ws->ctrA, 0, NB * sizeof(unsigned), stream);

  kA<<<1088, 256, 0, stream>>>((const float4*)tok, wstart, bstart, wend, bend,
                               seq, Wspan, bspan, Wnsp, bnsp, out, ws);
  kCD<<<NB*MS, 1024, 0, stream>>>((const float4*)tok, Wspan, bspan,
                                  seq, Wpol, bpol, out, ws);
}

// Round 7
// 79.577 us; speedup vs baseline: 5.1518x; 5.1518x over previous
//
#include <hip/hip_runtime.h>
#include <math.h>

#define NB 64
#define SS 512
#define HH 768
#define LL 20
#define MS 8
#define NSPC 9   // MAX_SPANS+1

// ---- output layout (floats), reference return order ----
#define OFF_START 0
#define OFF_END   (NB*SS)
#define OFF_SPANS (2*NB*SS)
#define OFF_NSP   (2*NB*SS + NB*LL)
#define OFF_POL   (2*NB*SS + NB*LL + NB*NSPC)
#define OFF_SOH   (2*NB*SS + 2*NB*LL + NB*NSPC)
#define OFF_EOH   (3*NB*SS + 2*NB*LL + NB*NSPC)
#define OFF_LOH   (4*NB*SS + 2*NB*LL + NB*NSPC)

struct WS {
  float fsl[NB][LL];          // full_seq_logits
  float mls[NB][MS][LL];      // per-span softmax rows
  int   nspans[NB];
  int   fslarg[NB];           // argmax(full_seq_logits)
  int   cnt[NB];
  int   out_s[NB][MS];
  int   out_e[NB][MS];
  int   slabel[NB][MS];
  float candSV[NB][16][MS];   // per-token-block top-8 candidates (starts)
  int   candSI[NB][16][MS];
  float candEV[NB][16][MS];   // (ends)
  int   candEI[NB][16][MS];
};

// ---------------- kA: token logits (8 rows/wave) + per-block top-8 + seq proj ----------------
// blocks [0,1024): 32 rows each (4 waves x 8 rows); 16 blocks per item; each
// writes its local top-8 candidates (starts & ends) to ws — plain stores, the
// kernel boundary synchronizes. blocks [1024,1088): per-item seq projections.
__global__ __launch_bounds__(256) void kA(
    const float4* __restrict__ tok,
    const float* __restrict__ wstart, const float* __restrict__ bstart,
    const float* __restrict__ wend,  const float* __restrict__ bend,
    const float* __restrict__ seq,
    const float* __restrict__ Wspan, const float* __restrict__ bspan,
    const float* __restrict__ Wnsp,  const float* __restrict__ bnsp,
    float* __restrict__ out, WS* __restrict__ ws)
{
  int t = threadIdx.x;
  int wave = t >> 6, lane = t & 63;

  if (blockIdx.x < 1024) {
    int b = blockIdx.x >> 4;
    int blk = blockIdx.x & 15;
    __shared__ float4 shs[HH/4], she[HH/4];
    __shared__ float lvS[32], lvE[32];
    const float4* wsg = (const float4*)wstart;
    const float4* weg = (const float4*)wend;
    for (int i = t; i < HH/4; i += 256) { shs[i] = wsg[i]; she[i] = weg[i]; }
    __syncthreads();
    int r0 = blockIdx.x * 32 + wave * 8;
    const float4* base = tok + (size_t)r0 * (HH/4);
    float as[8] = {0.f,0.f,0.f,0.f,0.f,0.f,0.f,0.f};
    float ae[8] = {0.f,0.f,0.f,0.f,0.f,0.f,0.f,0.f};
    #pragma unroll
    for (int k = 0; k < 3; ++k) {
      int idx = k*64 + lane;
      float4 a = shs[idx], c = she[idx];
      #pragma unroll
      for (int j = 0; j < 8; ++j) {
        float4 x = base[(size_t)j * (HH/4) + idx];
        as[j] += x.x*a.x + x.y*a.y + x.z*a.z + x.w*a.w;
        ae[j] += x.x*c.x + x.y*c.y + x.z*c.z + x.w*c.w;
      }
    }
    float b0 = bstart[0], b1 = bend[0];
    #pragma unroll
    for (int j = 0; j < 8; ++j) {
      float a = as[j], e = ae[j];
      for (int off = 32; off >= 1; off >>= 1) { a += __shfl_down(a, off); e += __shfl_down(e, off); }
      if (lane == 0) {
        out[OFF_START + r0 + j] = a + b0;
        out[OFF_END   + r0 + j] = e + b1;
        int slot = wave*8 + j;
        lvS[slot] = a + b0; lvE[slot] = e + b1;
      }
    }
    __syncthreads();
    // per-block top-8 via rank selection (wave 0 -> S, wave 1 -> E).
    // local row index = slot; global row = blk*32 + slot (monotone in slot,
    // so (v desc, idx asc) ordering is preserved).
    if (wave < 2) {
      float v = -INFINITY; int idx = 0x7fffffff;
      if (lane < 32) {
        v = wave ? lvE[lane] : lvS[lane];
        idx = blk*32 + lane;
      }
      int rank = 0;
      #pragma unroll
      for (int j = 0; j < 32; ++j) {
        float vj = __shfl(v, j); int ij = __shfl(idx, j);
        if (vj > v || (vj == v && ij < idx)) ++rank;
      }
      if (lane < 32 && rank < MS) {
        if (wave == 0) { ws->candSV[b][blk][rank] = v; ws->candSI[b][blk][rank] = idx; }
        else           { ws->candEV[b][blk][rank] = v; ws->candEI[b][blk][rank] = idx; }
      }
    }
  } else {
    int b = blockIdx.x - 1024;
    __shared__ float sh[HH];
    __shared__ float logits[LL + NSPC];
    for (int i = t; i < HH; i += 256) sh[i] = seq[b*HH + i];
    __syncthreads();
    for (int o = wave; o < LL + NSPC; o += 4) {
      float acc = 0.f;
      if (o < LL) {
        for (int k = 0; k < HH/64; ++k) { int h = lane + 64*k; acc += sh[h] * Wspan[h*LL + o]; }
      } else {
        int j = o - LL;
        for (int k = 0; k < HH/64; ++k) { int h = lane + 64*k; acc += sh[h] * Wnsp[h*NSPC + j]; }
      }
      for (int off = 32; off >= 1; off >>= 1) acc += __shfl_down(acc, off);
      if (lane == 0) logits[o] = acc + (o < LL ? bspan[o] : bnsp[o - LL]);
    }
    __syncthreads();
    if (t == 0) {
      int bi = 0; float bv = logits[LL];
      #pragma unroll
      for (int j = 1; j < NSPC; ++j) { float v = logits[LL + j]; if (v > bv) { bv = v; bi = j; } }
      ws->nspans[b] = bi;
      int fi = 0; float fv = logits[0];
      #pragma unroll
      for (int j = 1; j < LL; ++j) { float v = logits[j]; if (v > fv) { fv = v; fi = j; } }
      ws->fslarg[b] = fi;
    }
    if (t < LL)  ws->fsl[b][t] = logits[t];
    if (t < NSPC) out[OFF_NSP + b*NSPC + t] = logits[LL + t];
  }
}

// ---------------- kB: merge candidates + span selection + one-hots ----------------
// one 256-thread block per item. reads 2x128 candidates, not the full logits.
__global__ __launch_bounds__(256) void kB(
    float* __restrict__ out, WS* __restrict__ ws)
{
  int b = blockIdx.x;
  int t = threadIdx.x;
  int wave = t >> 6, lane = t & 63;

  __shared__ int topI[2][MS];
  __shared__ int sh_cnt, sh_single;
  __shared__ int sh_os[MS], sh_oe[MS];

  // extraction: wave 0 -> starts, wave 1 -> ends; 128 candidates, 2/lane
  if (wave < 2) {
    const float* cv = wave ? &ws->candEV[b][0][0] : &ws->candSV[b][0][0];
    const int*   ci = wave ? &ws->candEI[b][0][0] : &ws->candSI[b][0][0];
    float c0v = cv[lane], c1v = cv[lane + 64];
    int   c0i = ci[lane], c1i = ci[lane + 64];
    #pragma unroll
    for (int k = 0; k < MS; ++k) {
      float lv = c0v; int li = c0i;
      if (c1v > lv || (c1v == lv && c1i < li)) { lv = c1v; li = c1i; }
      #pragma unroll
      for (int m = 32; m >= 1; m >>= 1) {
        float ov = __shfl_xor(lv, m); int oi = __shfl_xor(li, m);
        if (ov > lv || (ov == lv && oi < li)) { lv = ov; li = oi; }
      }
      if (lane == 0) topI[wave][k] = li;
      if (c0i == li) c0v = -INFINITY;
      if (c1i == li) c1v = -INFINITY;
    }
  }
  __syncthreads();

  // selection automaton: wave 0, wave-uniform state
  if (wave == 0) {
    int n = ws->nspans[b];
    int xs = SS, xe = SS;
    if (lane < MS && lane < n) { xs = topI[0][lane]; xe = topI[1][lane]; }
    int rs = 0, re = 0;
    #pragma unroll
    for (int j = 0; j < MS; ++j) {
      int xj = __shfl(xs, j);
      if (xj < xs || (xj == xs && j < lane)) ++rs;
      int yj = __shfl(xe, j);
      if (yj < xe || (yj == xe && j < lane)) ++re;
    }
    int ss_srt = 0, es_srt = 0;
    #pragma unroll
    for (int j = 0; j < MS; ++j) {
      int xj = __shfl(xs, j); int rj = __shfl(rs, j);
      if (rj == lane) ss_srt = xj;
      int yj = __shfl(xe, j); int qj = __shfl(re, j);
      if (qj == lane) es_srt = yj;
    }
    int si = 0, ei = 0, last = 0, rem = n, cnt = 0;
    int my_os = 0, my_oe = 0;
    for (int it = 0; it < 2*MS; ++it) {
      bool active = (rem > 0) && (si < n) && (ei < n);
      int s = __shfl(ss_srt, si < MS ? si : MS - 1);
      int e = __shfl(es_srt, ei < MS ? ei : MS - 1);
      bool accept = active && (e > s) && (s >= last);
      bool ince = active && !accept && (e <= s);
      bool incs = active && !accept && (e > s);
      if (accept) {
        if (lane == cnt) { my_os = s; my_oe = e; }
        last = e; ++cnt; --rem; ++si; ++ei;
      } else {
        si += incs ? 1 : 0; ei += ince ? 1 : 0;
      }
    }
    if (lane < MS) {
      sh_os[lane] = my_os; sh_oe[lane] = my_oe;
      ws->out_s[b][lane] = my_os; ws->out_e[b][lane] = my_oe;
    }
    if (lane == 0) {
      sh_cnt = cnt; sh_single = (ws->nspans[b] <= 1) ? 1 : 0;
      ws->cnt[b] = cnt;
    }
  }
  __syncthreads();

  int cnt = sh_cnt, single = sh_single;
  #pragma unroll
  for (int pp = 0; pp < 2; ++pp) {
    int pos = t + pp * 256;
    float sval = 0.f, eval = 0.f;
    if (single) {
      if (pos == topI[0][0]) sval = 1.f;   // first-occurrence argmax
      if (pos == topI[1][0]) eval = 1.f;
    } else {
      for (int i = 0; i < cnt; ++i) {
        if (pos == sh_os[i]) sval = 1.f;
        if (pos == sh_oe[i]) eval = 1.f;
      }
    }
    out[OFF_SOH + b*SS + pos] = sval;
    out[OFF_EOH + b*SS + pos] = eval;
  }
}

// ---------------- kC: span mean-pool + per-span softmax (parallel spans) ----------------
__global__ __launch_bounds__(1024) void kC(
    const float4* __restrict__ tok,
    const float* __restrict__ Wspan, const float* __restrict__ bspan,
    WS* __restrict__ ws)
{
  int b = blockIdx.x >> 3;
  int i = blockIdx.x & (MS - 1);
  if (i >= ws->cnt[b]) return;    // uniform per block
  int s0 = ws->out_s[b][i], e0 = ws->out_e[b][i];
  int t = threadIdx.x;
  int g = t >> 8;        // row group 0..3
  int tid = t & 255;

  __shared__ float4 part[4][HH/4];   // 12 KB
  __shared__ float pooled[HH];
  __shared__ float lg[LL];

  if (tid < HH/4) {
    float4 acc = make_float4(0.f, 0.f, 0.f, 0.f);
    const float4* base = tok + (size_t)b * SS * (HH/4) + tid;
    #pragma unroll 4
    for (int r = s0 + g; r <= e0; r += 4) {
      float4 x = base[(size_t)r * (HH/4)];
      acc.x += x.x; acc.y += x.y; acc.z += x.z; acc.w += x.w;
    }
    part[g][tid] = acc;
  }
  __syncthreads();

  if (t < HH/4) {
    float4 p0 = part[0][t], p1 = part[1][t], p2 = part[2][t], p3 = part[3][t];
    float inv = 1.f / (float)(e0 - s0 + 1);
    float4 s;
    s.x = (p0.x + p1.x + p2.x + p3.x) * inv;
    s.y = (p0.y + p1.y + p2.y + p3.y) * inv;
    s.z = (p0.z + p1.z + p2.z + p3.z) * inv;
    s.w = (p0.w + p1.w + p2.w + p3.w) * inv;
    ((float4*)pooled)[t] = s;
  }
  __syncthreads();

  int wave = t >> 6, lane = t & 63;
  for (int l = wave; l < LL; l += 16) {
    float acc = 0.f;
    for (int k = 0; k < HH/64; ++k) { int h = lane + 64*k; acc += pooled[h] * Wspan[h*LL + l]; }
    for (int off = 32; off >= 1; off >>= 1) acc += __shfl_down(acc, off);
    if (lane == 0) lg[l] = acc + bspan[l];
  }
  __syncthreads();

  if (t == 0) {
    float v[LL]; float mx = -INFINITY;
    #pragma unroll
    for (int l = 0; l < LL; ++l) { v[l] = lg[l]; mx = fmaxf(mx, v[l]); }
    int am = 0; float av = v[0];
    #pragma unroll
    for (int l = 1; l < LL; ++l) if (v[l] > av) { av = v[l]; am = l; }
    float sum = 0.f;
    #pragma unroll
    for (int l = 0; l < LL; ++l) { v[l] = expf(v[l] - mx); sum += v[l]; }
    float isum = 1.f / sum;
    #pragma unroll
    for (int l = 0; l < LL; ++l) ws->mls[b][i][l] = v[l] * isum;
    ws->slabel[b][i] = am;
  }
}

// ---------------- kD: combine + pol_logits ----------------
__global__ __launch_bounds__(256) void kD(
    const float* __restrict__ seq,
    const float* __restrict__ Wpol, const float* __restrict__ bpol,
    float* __restrict__ out, WS* __restrict__ ws)
{
  int b = blockIdx.x;
  int t = threadIdx.x;
  __shared__ float sp[LL];
  __shared__ float fsl_soft[LL];
  int n = ws->nspans[b];
  int single = (n <= 1) ? 1 : 0;
  int cnt = ws->cnt[b];
  int fa = ws->fslarg[b];
  if (t == 0) {
    float lg[LL]; float mx = -INFINITY;
    #pragma unroll
    for (int l = 0; l < LL; ++l) { lg[l] = ws->fsl[b][l]; mx = fmaxf(mx, lg[l]); }
    float sum = 0.f;
    #pragma unroll
    for (int l = 0; l < LL; ++l) { lg[l] = expf(lg[l] - mx); sum += lg[l]; }
    float isum = 1.f / sum;
    #pragma unroll
    for (int l = 0; l < LL; ++l) fsl_soft[l] = lg[l] * isum;
  }
  __syncthreads();
  if (t < LL) {
    float v;
    if (single) v = fsl_soft[t];
    else if (cnt > 0) { v = -INFINITY; for (int i = 0; i < cnt; ++i) v = fmaxf(v, ws->mls[b][i][t]); }
    else v = 0.f;
    sp[t] = v;
    out[OFF_SPANS + b*LL + t] = v;
    float lo = 0.f;
    if (single || cnt == 0) lo = (t == fa) ? 1.f : 0.f;
    else { for (int i = 0; i < cnt; ++i) if (ws->slabel[b][i] == t) lo = 1.f; }
    out[OFF_LOH + b*LL + t] = lo;
  }
  __syncthreads();
  int wave = t >> 6, lane = t & 63;
  const float* seqb = seq + b*HH;
  for (int l = wave; l < LL; l += 4) {
    float acc = 0.f;
    for (int k = 0; k < 13; ++k) {
      int h = lane + 64*k;
      if (h < HH + LL) {
        float v = (h < HH) ? seqb[h] : sp[h - HH];
        acc += v * Wpol[h*LL + l];
      }
    }
    for (int off = 32; off >= 1; off >>= 1) acc += __shfl_down(acc, off);
    if (lane == 0) out[OFF_POL + b*LL + l] = acc + bpol[l];
  }
}

extern "C" void kernel_launch(void* const* d_in, const int* in_sizes, int n_in,
                              void* d_out, int out_size, void* d_ws, size_t ws_size,
                              hipStream_t stream)
{
  const float* tok    = (const float*)d_in[0];
  const float* seq    = (const float*)d_in[1];
  const float* wstart = (const float*)d_in[2];
  const float* bstart = (const float*)d_in[3];
  const float* wend   = (const float*)d_in[4];
  const float* bend   = (const float*)d_in[5];
  const float* Wnsp   = (const float*)d_in[6];
  const float* bnsp   = (const float*)d_in[7];
  const float* Wspan  = (const float*)d_in[8];
  const float* bspan  = (const float*)d_in[9];
  const float* Wpol   = (const float*)d_in[10];
  const float* bpol   = (const float*)d_in[11];
  float* out = (float*)d_out;
  WS* ws = (WS*)d_ws;

  kA<<<1088, 256, 0, stream>>>((const float4*)tok, wstart, bstart, wend, bend,
                               seq, Wspan, bspan, Wnsp, bnsp, out, ws);
  kB<<<NB, 256, 0, stream>>>(out, ws);
  kC<<<NB*MS, 1024, 0, stream>>>((const float4*)tok, Wspan, bspan, ws);
  kD<<<NB, 256, 0, stream>>>(seq, Wpol, bpol, out, ws);
}

// Round 8
// 77.200 us; speedup vs baseline: 5.3104x; 1.0308x over previous
//
#include <hip/hip_runtime.h>
#include <math.h>

#define NB 64
#define SS 512
#define HH 768
#define LL 20
#define MS 8
#define NSPC 9   // MAX_SPANS+1

// ---- output layout (floats), reference return order ----
#define OFF_START 0
#define OFF_END   (NB*SS)
#define OFF_SPANS (2*NB*SS)
#define OFF_NSP   (2*NB*SS + NB*LL)
#define OFF_POL   (2*NB*SS + NB*LL + NB*NSPC)
#define OFF_SOH   (2*NB*SS + 2*NB*LL + NB*NSPC)
#define OFF_EOH   (3*NB*SS + 2*NB*LL + NB*NSPC)
#define OFF_LOH   (4*NB*SS + 2*NB*LL + NB*NSPC)

struct WS {
  float fsl[NB][LL];          // full_seq_logits
  float mls[NB][MS][LL];      // per-span softmax rows
  int   nspans[NB];
  int   fslarg[NB];           // argmax(full_seq_logits)
  int   cnt[NB];
  int   slabel[NB][MS];
  float candSV[NB][16][MS];   // per-token-block top-8 candidates (starts)
  int   candSI[NB][16][MS];
  float candEV[NB][16][MS];   // (ends)
  int   candEI[NB][16][MS];
};

// ---------------- kA: token logits (8 rows/wave) + per-block top-8 + seq proj ----------------
// blocks [0,1024): 32 rows each (4 waves x 8 rows); 16 blocks per item; each
// writes its local top-8 candidates (starts & ends) to ws — plain stores, the
// kernel boundary synchronizes. blocks [1024,1088): per-item seq projections.
__global__ __launch_bounds__(256) void kA(
    const float4* __restrict__ tok,
    const float* __restrict__ wstart, const float* __restrict__ bstart,
    const float* __restrict__ wend,  const float* __restrict__ bend,
    const float* __restrict__ seq,
    const float* __restrict__ Wspan, const float* __restrict__ bspan,
    const float* __restrict__ Wnsp,  const float* __restrict__ bnsp,
    float* __restrict__ out, WS* __restrict__ ws)
{
  int t = threadIdx.x;
  int wave = t >> 6, lane = t & 63;

  if (blockIdx.x < 1024) {
    int b = blockIdx.x >> 4;
    int blk = blockIdx.x & 15;
    __shared__ float4 shs[HH/4], she[HH/4];
    __shared__ float lvS[32], lvE[32];
    const float4* wsg = (const float4*)wstart;
    const float4* weg = (const float4*)wend;
    for (int i = t; i < HH/4; i += 256) { shs[i] = wsg[i]; she[i] = weg[i]; }
    __syncthreads();
    int r0 = blockIdx.x * 32 + wave * 8;
    const float4* base = tok + (size_t)r0 * (HH/4);
    float as[8] = {0.f,0.f,0.f,0.f,0.f,0.f,0.f,0.f};
    float ae[8] = {0.f,0.f,0.f,0.f,0.f,0.f,0.f,0.f};
    #pragma unroll
    for (int k = 0; k < 3; ++k) {
      int idx = k*64 + lane;
      float4 a = shs[idx], c = she[idx];
      #pragma unroll
      for (int j = 0; j < 8; ++j) {
        float4 x = base[(size_t)j * (HH/4) + idx];
        as[j] += x.x*a.x + x.y*a.y + x.z*a.z + x.w*a.w;
        ae[j] += x.x*c.x + x.y*c.y + x.z*c.z + x.w*c.w;
      }
    }
    float b0 = bstart[0], b1 = bend[0];
    #pragma unroll
    for (int j = 0; j < 8; ++j) {
      float a = as[j], e = ae[j];
      for (int off = 32; off >= 1; off >>= 1) { a += __shfl_down(a, off); e += __shfl_down(e, off); }
      if (lane == 0) {
        out[OFF_START + r0 + j] = a + b0;
        out[OFF_END   + r0 + j] = e + b1;
        int slot = wave*8 + j;
        lvS[slot] = a + b0; lvE[slot] = e + b1;
      }
    }
    __syncthreads();
    // per-block top-8 via rank selection (wave 0 -> S, wave 1 -> E).
    if (wave < 2) {
      float v = -INFINITY; int idx = 0x7fffffff;
      if (lane < 32) {
        v = wave ? lvE[lane] : lvS[lane];
        idx = blk*32 + lane;
      }
      int rank = 0;
      #pragma unroll
      for (int j = 0; j < 32; ++j) {
        float vj = __shfl(v, j); int ij = __shfl(idx, j);
        if (vj > v || (vj == v && ij < idx)) ++rank;
      }
      if (lane < 32 && rank < MS) {
        if (wave == 0) { ws->candSV[b][blk][rank] = v; ws->candSI[b][blk][rank] = idx; }
        else           { ws->candEV[b][blk][rank] = v; ws->candEI[b][blk][rank] = idx; }
      }
    }
  } else {
    int b = blockIdx.x - 1024;
    __shared__ float sh[HH];
    __shared__ float logits[LL + NSPC];
    for (int i = t; i < HH; i += 256) sh[i] = seq[b*HH + i];
    __syncthreads();
    for (int o = wave; o < LL + NSPC; o += 4) {
      float acc = 0.f;
      if (o < LL) {
        for (int k = 0; k < HH/64; ++k) { int h = lane + 64*k; acc += sh[h] * Wspan[h*LL + o]; }
      } else {
        int j = o - LL;
        for (int k = 0; k < HH/64; ++k) { int h = lane + 64*k; acc += sh[h] * Wnsp[h*NSPC + j]; }
      }
      for (int off = 32; off >= 1; off >>= 1) acc += __shfl_down(acc, off);
      if (lane == 0) logits[o] = acc + (o < LL ? bspan[o] : bnsp[o - LL]);
    }
    __syncthreads();
    if (t == 0) {
      int bi = 0; float bv = logits[LL];
      #pragma unroll
      for (int j = 1; j < NSPC; ++j) { float v = logits[LL + j]; if (v > bv) { bv = v; bi = j; } }
      ws->nspans[b] = bi;
      int fi = 0; float fv = logits[0];
      #pragma unroll
      for (int j = 1; j < LL; ++j) { float v = logits[j]; if (v > fv) { fv = v; fi = j; } }
      ws->fslarg[b] = fi;
    }
    if (t < LL)  ws->fsl[b][t] = logits[t];
    if (t < NSPC) out[OFF_NSP + b*NSPC + t] = logits[LL + t];
  }
}

// ---------------- kC: merge+select (redundant per block) + one-hots + pool + softmax ----------------
// grid = NB*MS; block (b,i). All 8 blocks of item b deterministically recompute
// the merge + selection automaton from ws->cand* (shuffle-only, ~few hundred
// cycles); block (b,0) writes one-hots and cnt; blocks with i < cnt pool span i.
__global__ __launch_bounds__(1024) void kC(
    const float4* __restrict__ tok,
    const float* __restrict__ Wspan, const float* __restrict__ bspan,
    float* __restrict__ out, WS* __restrict__ ws)
{
  int b = blockIdx.x >> 3;
  int i = blockIdx.x & (MS - 1);
  int t = threadIdx.x;
  int wave = t >> 6, lane = t & 63;

  __shared__ int topI[2][MS];
  __shared__ int sh_cnt, sh_single;
  __shared__ int sh_os[MS], sh_oe[MS];

  // extraction: wave 0 -> starts, wave 1 -> ends; 128 candidates, 2/lane
  if (wave < 2) {
    const float* cv = wave ? &ws->candEV[b][0][0] : &ws->candSV[b][0][0];
    const int*   ci = wave ? &ws->candEI[b][0][0] : &ws->candSI[b][0][0];
    float c0v = cv[lane], c1v = cv[lane + 64];
    int   c0i = ci[lane], c1i = ci[lane + 64];
    #pragma unroll
    for (int k = 0; k < MS; ++k) {
      float lv = c0v; int li = c0i;
      if (c1v > lv || (c1v == lv && c1i < li)) { lv = c1v; li = c1i; }
      #pragma unroll
      for (int m = 32; m >= 1; m >>= 1) {
        float ov = __shfl_xor(lv, m); int oi = __shfl_xor(li, m);
        if (ov > lv || (ov == lv && oi < li)) { lv = ov; li = oi; }
      }
      if (lane == 0) topI[wave][k] = li;
      if (c0i == li) c0v = -INFINITY;
      if (c1i == li) c1v = -INFINITY;
    }
  }
  __syncthreads();

  // selection automaton: wave 0, wave-uniform state
  if (wave == 0) {
    int n = ws->nspans[b];
    int xs = SS, xe = SS;
    if (lane < MS && lane < n) { xs = topI[0][lane]; xe = topI[1][lane]; }
    int rs = 0, re = 0;
    #pragma unroll
    for (int j = 0; j < MS; ++j) {
      int xj = __shfl(xs, j);
      if (xj < xs || (xj == xs && j < lane)) ++rs;
      int yj = __shfl(xe, j);
      if (yj < xe || (yj == xe && j < lane)) ++re;
    }
    int ss_srt = 0, es_srt = 0;
    #pragma unroll
    for (int j = 0; j < MS; ++j) {
      int xj = __shfl(xs, j); int rj = __shfl(rs, j);
      if (rj == lane) ss_srt = xj;
      int yj = __shfl(xe, j); int qj = __shfl(re, j);
      if (qj == lane) es_srt = yj;
    }
    int si = 0, ei = 0, last = 0, rem = n, cnt = 0;
    int my_os = 0, my_oe = 0;
    for (int it = 0; it < 2*MS; ++it) {
      bool active = (rem > 0) && (si < n) && (ei < n);
      int s = __shfl(ss_srt, si < MS ? si : MS - 1);
      int e = __shfl(es_srt, ei < MS ? ei : MS - 1);
      bool accept = active && (e > s) && (s >= last);
      bool ince = active && !accept && (e <= s);
      bool incs = active && !accept && (e > s);
      if (accept) {
        if (lane == cnt) { my_os = s; my_oe = e; }
        last = e; ++cnt; --rem; ++si; ++ei;
      } else {
        si += incs ? 1 : 0; ei += ince ? 1 : 0;
      }
    }
    if (lane < MS) { sh_os[lane] = my_os; sh_oe[lane] = my_oe; }
    if (lane == 0) { sh_cnt = cnt; sh_single = (n <= 1) ? 1 : 0; }
  }
  __syncthreads();

  int cnt = sh_cnt, single = sh_single;

  // block (b,0): one-hots + publish cnt for kD
  if (i == 0) {
    if (t < SS) {
      int pos = t;
      float sval = 0.f, eval = 0.f;
      if (single) {
        if (pos == topI[0][0]) sval = 1.f;   // first-occurrence argmax
        if (pos == topI[1][0]) eval = 1.f;
      } else {
        for (int k = 0; k < cnt; ++k) {
          if (pos == sh_os[k]) sval = 1.f;
          if (pos == sh_oe[k]) eval = 1.f;
        }
      }
      out[OFF_SOH + b*SS + pos] = sval;
      out[OFF_EOH + b*SS + pos] = eval;
    }
    if (t == 0) ws->cnt[b] = cnt;
  }

  if (i >= cnt) return;
  int s0 = sh_os[i], e0 = sh_oe[i];

  int g = t >> 8;        // row group 0..3
  int tid = t & 255;
  __shared__ float4 part[4][HH/4];   // 12 KB
  __shared__ float pooled[HH];
  __shared__ float lg[LL];

  if (tid < HH/4) {
    float4 acc = make_float4(0.f, 0.f, 0.f, 0.f);
    const float4* base = tok + (size_t)b * SS * (HH/4) + tid;
    #pragma unroll 4
    for (int r = s0 + g; r <= e0; r += 4) {
      float4 x = base[(size_t)r * (HH/4)];
      acc.x += x.x; acc.y += x.y; acc.z += x.z; acc.w += x.w;
    }
    part[g][tid] = acc;
  }
  __syncthreads();

  if (t < HH/4) {
    float4 p0 = part[0][t], p1 = part[1][t], p2 = part[2][t], p3 = part[3][t];
    float inv = 1.f / (float)(e0 - s0 + 1);
    float4 s;
    s.x = (p0.x + p1.x + p2.x + p3.x) * inv;
    s.y = (p0.y + p1.y + p2.y + p3.y) * inv;
    s.z = (p0.z + p1.z + p2.z + p3.z) * inv;
    s.w = (p0.w + p1.w + p2.w + p3.w) * inv;
    ((float4*)pooled)[t] = s;
  }
  __syncthreads();

  for (int l = wave; l < LL; l += 16) {
    float acc = 0.f;
    for (int k = 0; k < HH/64; ++k) { int h = lane + 64*k; acc += pooled[h] * Wspan[h*LL + l]; }
    for (int off = 32; off >= 1; off >>= 1) acc += __shfl_down(acc, off);
    if (lane == 0) lg[l] = acc + bspan[l];
  }
  __syncthreads();

  if (t == 0) {
    float v[LL]; float mx = -INFINITY;
    #pragma unroll
    for (int l = 0; l < LL; ++l) { v[l] = lg[l]; mx = fmaxf(mx, v[l]); }
    int am = 0; float av = v[0];
    #pragma unroll
    for (int l = 1; l < LL; ++l) if (v[l] > av) { av = v[l]; am = l; }
    float sum = 0.f;
    #pragma unroll
    for (int l = 0; l < LL; ++l) { v[l] = expf(v[l] - mx); sum += v[l]; }
    float isum = 1.f / sum;
    #pragma unroll
    for (int l = 0; l < LL; ++l) ws->mls[b][i][l] = v[l] * isum;
    ws->slabel[b][i] = am;
  }
}

// ---------------- kD: combine + pol_logits ----------------
__global__ __launch_bounds__(256) void kD(
    const float* __restrict__ seq,
    const float* __restrict__ Wpol, const float* __restrict__ bpol,
    float* __restrict__ out, WS* __restrict__ ws)
{
  int b = blockIdx.x;
  int t = threadIdx.x;
  __shared__ float sp[LL];
  __shared__ float fsl_soft[LL];
  int n = ws->nspans[b];
  int single = (n <= 1) ? 1 : 0;
  int cnt = ws->cnt[b];
  int fa = ws->fslarg[b];
  if (t == 0) {
    float lg[LL]; float mx = -INFINITY;
    #pragma unroll
    for (int l = 0; l < LL; ++l) { lg[l] = ws->fsl[b][l]; mx = fmaxf(mx, lg[l]); }
    float sum = 0.f;
    #pragma unroll
    for (int l = 0; l < LL; ++l) { lg[l] = expf(lg[l] - mx); sum += lg[l]; }
    float isum = 1.f / sum;
    #pragma unroll
    for (int l = 0; l < LL; ++l) fsl_soft[l] = lg[l] * isum;
  }
  __syncthreads();
  if (t < LL) {
    float v;
    if (single) v = fsl_soft[t];
    else if (cnt > 0) { v = -INFINITY; for (int i = 0; i < cnt; ++i) v = fmaxf(v, ws->mls[b][i][t]); }
    else v = 0.f;
    sp[t] = v;
    out[OFF_SPANS + b*LL + t] = v;
    float lo = 0.f;
    if (single || cnt == 0) lo = (t == fa) ? 1.f : 0.f;
    else { for (int i = 0; i < cnt; ++i) if (ws->slabel[b][i] == t) lo = 1.f; }
    out[OFF_LOH + b*LL + t] = lo;
  }
  __syncthreads();
  int wave = t >> 6, lane = t & 63;
  const float* seqb = seq + b*HH;
  for (int l = wave; l < LL; l += 4) {
    float acc = 0.f;
    for (int k = 0; k < 13; ++k) {
      int h = lane + 64*k;
      if (h < HH + LL) {
        float v = (h < HH) ? seqb[h] : sp[h - HH];
        acc += v * Wpol[h*LL + l];
      }
    }
    for (int off = 32; off >= 1; off >>= 1) acc += __shfl_down(acc, off);
    if (lane == 0) out[OFF_POL + b*LL + l] = acc + bpol[l];
  }
}

extern "C" void kernel_launch(void* const* d_in, const int* in_sizes, int n_in,
                              void* d_out, int out_size, void* d_ws, size_t ws_size,
                              hipStream_t stream)
{
  const float* tok    = (const float*)d_in[0];
  const float* seq    = (const float*)d_in[1];
  const float* wstart = (const float*)d_in[2];
  const float* bstart = (const float*)d_in[3];
  const float* wend   = (const float*)d_in[4];
  const float* bend   = (const float*)d_in[5];
  const float* Wnsp   = (const float*)d_in[6];
  const float* bnsp   = (const float*)d_in[7];
  const float* Wspan  = (const float*)d_in[8];
  const float* bspan  = (const float*)d_in[9];
  const float* Wpol   = (const float*)d_in[10];
  const float* bpol   = (const float*)d_in[11];
  float* out = (float*)d_out;
  WS* ws = (WS*)d_ws;

  kA<<<1088, 256, 0, stream>>>((const float4*)tok, wstart, bstart, wend, bend,
                               seq, Wspan, bspan, Wnsp, bnsp, out, ws);
  kC<<<NB*MS, 1024, 0, stream>>>((const float4*)tok, Wspan, bspan, out, ws);
  kD<<<NB, 256, 0, stream>>>(seq, Wpol, bpol, out, ws);
}